// Round 16
// baseline (1393.955 us; speedup 1.0000x reference)
//
#include <hip/hip_runtime.h>
#include <stdint.h>

#define T_TOK 4096
#define H_DIM 1024
#define E_EXP 8
#define DFF_D 4096
#define HROWS 10240
#define NT 40
#define G1_ITEMS 640          // 16 ct * NT
#define TR2_ITEMS 2048        // w2: 8 e * 4 nt * 64 kt
#define GATE_BLKS 512
#define TR1_ITEMS 2048        // w1: 8 e * 16 nt * 16 kt

typedef __attribute__((ext_vector_type(4))) float f32x4;
typedef __attribute__((ext_vector_type(8))) __bf16 bf16x8;

static __device__ __forceinline__ unsigned short f2bf(float f) {
  union { float f; unsigned u; } v; v.f = f;
  unsigned r = v.u + 0x7FFFu + ((v.u >> 16) & 1u);
  return (unsigned short)(r >> 16);
}
static __device__ __forceinline__ float bf2f(unsigned short u) {
  union { unsigned u; float f; } v; v.u = ((unsigned)u) << 16; return v.f;
}
static __device__ __forceinline__ void load_lds16(const void* g, void* l) {
  __builtin_amdgcn_global_load_lds(
      (const __attribute__((address_space(1))) unsigned int*)g,
      (__attribute__((address_space(3))) unsigned int*)l, 16, 0, 0);
}

#define MEMF() asm volatile("" ::: "memory")
#define BAR()  { MEMF(); __builtin_amdgcn_s_barrier(); MEMF(); }
#define VM0()  asm volatile("s_waitcnt vmcnt(0)" ::: "memory")
#define SP1()  __builtin_amdgcn_s_setprio(1)
#define SP0()  __builtin_amdgcn_s_setprio(0)

// ---- R11-verified: transpose 64x256 src tile -> one 32KB consumption-order B tile ----
static __device__ __forceinline__ void tr_tile_to_tiled(
    unsigned short* __restrict__ tile16,         // LDS [64][260] ushort
    const float* __restrict__ src, int src_ld,
    int r0, int c0,                              // src row(k)/col(n) base
    unsigned short* __restrict__ tile_out,       // 32KB block
    int tid) {
  const int w = tid >> 6, lane = tid & 63;
#pragma unroll
  for (int i = 0; i < 8; ++i) {
    const int row = w * 8 + i;
    float4 v = *(const float4*)&src[(size_t)(r0 + row) * src_ld + c0 + 4 * lane];
    ushort4 o;
    o.x = f2bf(v.x); o.y = f2bf(v.y); o.z = f2bf(v.z); o.w = f2bf(v.w);
    *(ushort4*)&tile16[row * 260 + 4 * lane] = o;
  }
  __syncthreads();
  const int r0t = ((tid >> 7) << 4) + ((tid >> 2) & 15);
  const int kbt = (((tid >> 6) & 1) << 5) + (((tid & 3) << 3) ^ (((tid >> 5) & 1) << 4));
#pragma unroll
  for (int half = 0; half < 2; ++half)
#pragma unroll
    for (int j = 0; j < 2; ++j) {
      const int c = half * 128 + 64 * j + r0t;
      unsigned ow[4];
#pragma unroll
      for (int p = 0; p < 4; ++p)
        ow[p] = (unsigned)tile16[(kbt + 2 * p) * 260 + c]
              | ((unsigned)tile16[(kbt + 2 * p + 1) * 260 + c] << 16);
      *(uint4*)((char*)tile_out + half * 16384 + j * 8192 + tid * 16) = *(uint4*)ow;
    }
}

// ---------------- fused: gate (atomic-free) + w1 transpose ----------------
__global__ __launch_bounds__(512) void gate_tr1_kernel(
    const float* __restrict__ x, const float* __restrict__ gw,
    const float* __restrict__ gb,
    int* __restrict__ ids, int* __restrict__ locs, float* __restrict__ tokg,
    int* __restrict__ bcnt, float* __restrict__ partials,
    unsigned short* __restrict__ xb,
    const float* __restrict__ w1, unsigned short* __restrict__ w1t) {
  extern __shared__ char smem[];
  const int tid = threadIdx.x;
  const int blk = blockIdx.x;

  if (blk >= GATE_BLKS) {
    const int j = blk - GATE_BLKS;               // [0, 2048)
    const int e2 = j >> 8;
    const int jj = j & 255;
    const int nt = jj >> 4, kt = jj & 15;
    tr_tile_to_tiled((unsigned short*)smem,
                     w1 + (size_t)e2 * H_DIM * DFF_D, DFF_D,
                     kt * 64, nt * 256,
                     w1t + ((size_t)((e2 * 16 + nt) * 16 + kt)) * 16384,
                     tid);
    return;
  }

  // ---- gate (atomic-free, deterministic intra-block ranking) ----
  float (*probs_lds)[8] = (float(*)[8])smem;              // [8][8]
  int   (*topi_lds)[2]  = (int(*)[2])(smem + 256);        // [8][2]
  int*  locs_lds        = (int*)(smem + 320);             // [16]
  int*  cnt_lds         = (int*)(smem + 384);             // [8]
  const int lane = tid & 63, tl = tid >> 6;
  const int token = blk * 8 + tl;
  float a[8];
#pragma unroll
  for (int e = 0; e < 8; ++e) a[e] = 0.f;
#pragma unroll
  for (int i = 0; i < 4; ++i) {
    const int k4 = i * 256 + lane * 4;
    float4 xv4 = *(const float4*)&x[(size_t)token * H_DIM + k4];
    ushort4 xo;
    xo.x = f2bf(xv4.x); xo.y = f2bf(xv4.y); xo.z = f2bf(xv4.z); xo.w = f2bf(xv4.w);
    *(ushort4*)&xb[(size_t)token * H_DIM + k4] = xo;
#pragma unroll
    for (int j = 0; j < 4; ++j) {
      const float xv = ((const float*)&xv4)[j];
      const float4* g = (const float4*)&gw[(size_t)(k4 + j) * 8];
      float4 g0 = g[0], g1 = g[1];
      a[0] += xv * g0.x; a[1] += xv * g0.y; a[2] += xv * g0.z; a[3] += xv * g0.w;
      a[4] += xv * g1.x; a[5] += xv * g1.y; a[6] += xv * g1.z; a[7] += xv * g1.w;
    }
  }
  for (int m = 32; m >= 1; m >>= 1) {
#pragma unroll
    for (int e = 0; e < 8; ++e) a[e] += __shfl_xor(a[e], m);
  }
  if (lane == 0) {
    float lg[8], p[8];
    float mx = -1e30f;
#pragma unroll
    for (int e = 0; e < 8; ++e) { lg[e] = a[e] + gb[e]; mx = lg[e] > mx ? lg[e] : mx; }
    float s = 0.f;
#pragma unroll
    for (int e = 0; e < 8; ++e) { p[e] = expf(lg[e] - mx); s += p[e]; }
    float inv = 1.f / s;
#pragma unroll
    for (int e = 0; e < 8; ++e) p[e] *= inv;
    int i0 = 0;
#pragma unroll
    for (int e = 1; e < 8; ++e) if (p[e] > p[i0]) i0 = e;
    int i1 = (i0 == 0) ? 1 : 0;
#pragma unroll
    for (int e = 0; e < 8; ++e) if (e != i0 && p[e] > p[i1]) i1 = e;
#pragma unroll
    for (int e = 0; e < 8; ++e) probs_lds[tl][e] = p[e];
    topi_lds[tl][0] = i0; topi_lds[tl][1] = i1;
  }
  __syncthreads();
  if (tid == 0) {
    int run[8];
#pragma unroll
    for (int e = 0; e < 8; ++e) run[e] = 0;
    for (int q = 0; q < 16; ++q) {
      const int e = topi_lds[q >> 1][q & 1];
      locs_lds[q] = run[e]++;
    }
#pragma unroll
    for (int e = 0; e < 8; ++e) cnt_lds[e] = run[e];
  }
  __syncthreads();
  if (tid < 16) {
    const int tt = tid >> 1, c = tid & 1;
    const int t2 = blk * 8 + tt;
    const int e = topi_lds[tt][c];
    ids[t2 * 2 + c]  = e;
    locs[t2 * 2 + c] = locs_lds[tid];
    tokg[t2 * 2 + c] = probs_lds[tt][e];
  }
  if (tid >= 16 && tid < 24) bcnt[blk * 8 + (tid - 16)] = cnt_lds[tid - 16];
  if (tid < 24) {
    int e = tid & 7, which = tid >> 3;
    float s = 0.f;
#pragma unroll
    for (int tt = 0; tt < 8; ++tt) {
      float pv = probs_lds[tt][e];
      bool m = (topi_lds[tt][0] == e) || (topi_lds[tt][1] == e);
      if (which == 0) s += pv;
      else if (which == 1) s += m ? 1.f : 0.f;
      else s += m ? pv : 0.f;
    }
    partials[blk * 24 + tid] = s;
  }
}

// ---------------- meta: scan + scatter + offsets/tilemap + aux ----------------
__global__ __launch_bounds__(1024) void meta_kernel(
    const int* __restrict__ bcnt, const int* __restrict__ ids,
    const int* __restrict__ locs, const float* __restrict__ tokg,
    const float* __restrict__ partials,
    int* __restrict__ counts, int* __restrict__ hoff, int* __restrict__ tmap,
    int* __restrict__ entry_token, float* __restrict__ entry_gate,
    int* __restrict__ slots, float* __restrict__ out_aux) {
  __shared__ int sc[8][513];
  __shared__ float red[24][33];
  const int tid = threadIdx.x;
#pragma unroll
  for (int j = 0; j < 4; ++j) {
    const int idx = tid + j * 1024;
    const int e = idx >> 9, b = idx & 511;
    sc[e][b] = bcnt[b * 8 + e];
  }
  __syncthreads();
  for (int off = 1; off < 512; off <<= 1) {
    int v[4];
#pragma unroll
    for (int j = 0; j < 4; ++j) {
      const int idx = tid + j * 1024;
      const int e = idx >> 9, b = idx & 511;
      v[j] = sc[e][b] + (b >= off ? sc[e][b - off] : 0);
    }
    __syncthreads();
#pragma unroll
    for (int j = 0; j < 4; ++j) {
      const int idx = tid + j * 1024;
      sc[idx >> 9][idx & 511] = v[j];
    }
    __syncthreads();
  }
  if (tid == 0) {
    int o = 0, nt = 0;
    for (int e = 0; e < E_EXP; ++e) {
      const int ce = sc[e][511];
      counts[e] = ce;
      hoff[e] = o;
      int rtc = (ce + 255) >> 8;
      o += rtc << 8;
      for (int rt = 0; rt < rtc; ++rt) tmap[nt++] = (e << 16) | rt;
    }
    hoff[E_EXP] = o;
    for (; nt < NT; ++nt) tmap[nt] = -1;
  }
  __syncthreads();
#pragma unroll
  for (int j = 0; j < 8; ++j) {
    const int idx = tid + j * 1024;
    const int t = idx >> 1, c = idx & 1, b = t >> 3;
    const int e = ids[t * 2 + c];
    const int slot = sc[e][b] - bcnt[b * 8 + e] + locs[t * 2 + c];
    entry_token[e * T_TOK + slot] = t;
    entry_gate[e * T_TOK + slot] = tokg[t * 2 + c];
    slots[t * 2 + c] = slot;
  }
  const int c = tid & 31, g = tid >> 5;
  if (c < 24) {
    float s = 0.f;
    for (int j = 0; j < 16; ++j) s += partials[(size_t)(g + j * 32) * 24 + c];
    red[c][g] = s;
  }
  __syncthreads();
  if (tid < 24) {
    float t2 = 0.f;
#pragma unroll
    for (int g2 = 0; g2 < 32; ++g2) t2 += red[tid][g2];
    red[tid][32] = t2;
  }
  __syncthreads();
  if (tid == 0) {
    float mean = 0.f;
    for (int e = 0; e < 8; ++e) mean += red[e][32];
    mean *= 0.125f;
    float var = 0.f;
    for (int e = 0; e < 8; ++e) { float d = red[e][32] - mean; var += d * d; }
    var *= (1.f / 7.f);
    float il = var * (1.f / 64.f);
    float lb = 0.f;
    for (int e = 0; e < 8; ++e)
      lb += (red[8 + e][32] / (float)T_TOK) * (red[16 + e][32] / (float)T_TOK);
    lb *= 8.f;
    out_aux[0] = il + lb;
  }
}

// ======== 256x256x64 grouped-GEMM, SINGLE-buffered LDS (64KB) -> 2 blocks/CU ========
// m97-style loop: stage-all -> vmcnt(0) -> barrier -> compute (reg reuse) -> barrier.
// Latency hidden by co-resident block (TLP), not counted vmcnt.
#define STG_A0s(m_) { char* lb_ = sA + wv*1024; \
  load_lds16(pa0s0 + (size_t)(m_)*128, lb_); load_lds16(pa0s1 + (size_t)(m_)*128, lb_ + 8192); }
#define STG_A1s(m_) { char* lb_ = sA + 16384 + wv*1024; \
  load_lds16(pa1s0 + (size_t)(m_)*128, lb_); load_lds16(pa1s1 + (size_t)(m_)*128, lb_ + 8192); }
#define STG_B0s(m_) { char* lb_ = sB + wv*1024; \
  load_lds16(pb0s0 + (size_t)(m_)*32768, lb_); load_lds16(pb0s1 + (size_t)(m_)*32768, lb_ + 8192); }
#define STG_B1s(m_) { char* lb_ = sB + 16384 + wv*1024; \
  load_lds16(pb1s0 + (size_t)(m_)*32768, lb_); load_lds16(pb1s1 + (size_t)(m_)*32768, lb_ + 8192); }

#define LDA8(DST, AD) \
  _Pragma("unroll") for (int mi = 0; mi < 4; ++mi) \
  _Pragma("unroll") for (int kk = 0; kk < 2; ++kk) \
    DST[mi][kk] = *(const bf16x8*)((AD) + (amfrag + mi) * 2048 + kk * 1024 + lane_off);
#define LDB4(DST, BD) \
  _Pragma("unroll") for (int ni = 0; ni < 2; ++ni) \
  _Pragma("unroll") for (int kk = 0; kk < 2; ++kk) \
    DST[ni][kk] = *(const bf16x8*)((BD) + (bnfrag + ni) * 2048 + kk * 1024 + lane_off);
#define MF16(ACC, AF, BF) \
  _Pragma("unroll") for (int mi = 0; mi < 4; ++mi) \
  _Pragma("unroll") for (int ni = 0; ni < 2; ++ni) \
  _Pragma("unroll") for (int kk = 0; kk < 2; ++kk) \
    ACC[mi][ni] = __builtin_amdgcn_mfma_f32_16x16x32_bf16(AF[mi][kk], BF[ni][kk], ACC[mi][ni], 0, 0, 0);

#define ACC_INIT() \
  f32x4 q00[4][2], q01[4][2], q10[4][2], q11[4][2]; \
  _Pragma("unroll") for (int mi = 0; mi < 4; ++mi) \
  _Pragma("unroll") for (int ni = 0; ni < 2; ++ni) { \
    q00[mi][ni] = (f32x4){0.f,0.f,0.f,0.f}; q01[mi][ni] = (f32x4){0.f,0.f,0.f,0.f}; \
    q10[mi][ni] = (f32x4){0.f,0.f,0.f,0.f}; q11[mi][ni] = (f32x4){0.f,0.f,0.f,0.f}; }

#define KLOOP_SB(KT) \
  for (int k = 0; k < (KT); ++k) { \
    STG_A0s(k); STG_A1s(k); STG_B0s(k); STG_B1s(k); \
    VM0(); \
    BAR(); \
    bf16x8 alo[4][2], ahi[4][2], blo[2][2], bhi[2][2]; \
    LDA8(alo, sA); LDB4(blo, sB); \
    SP1(); MF16(q00, alo, blo); SP0(); \
    LDB4(bhi, sB + 16384); \
    SP1(); MF16(q01, alo, bhi); SP0(); \
    LDA8(ahi, sA + 16384); \
    SP1(); MF16(q10, ahi, blo); SP0(); \
    SP1(); MF16(q11, ahi, bhi); SP0(); \
    BAR(); \
  }

// ---------------- GEMM1 (+ fused w2 transpose items in tail blocks) ----------------
__global__ __launch_bounds__(512, 4) void gemm1_kernel(
    const unsigned short* __restrict__ xb,    // [T][1024]
    const unsigned short* __restrict__ w1t,   // TILED [E][16 nt][16 kt][32KB]
    const float* __restrict__ b1,
    const int* __restrict__ counts, const int* __restrict__ hoff,
    const int* __restrict__ tmap, const int* __restrict__ entry_token,
    unsigned short* __restrict__ h,           // [HROWS][4096]
    const float* __restrict__ w2,             // [E][4096][1024] f32
    unsigned short* __restrict__ w2t)         // TILED [E][4 nt][64 kt][32KB]
{
  extern __shared__ char smem[];
  char* sA = smem;
  char* sB = smem + 32768;
  const int tid = threadIdx.x;
  const int item = blockIdx.x;

  if (item >= G1_ITEMS) {
    const int j = item - G1_ITEMS;            // [0, 2048)
    const int e2 = j >> 8;
    const int jj = j & 255;
    const int nt = jj >> 6, kt = jj & 63;
    tr_tile_to_tiled((unsigned short*)smem,
                     w2 + (size_t)e2 * DFF_D * H_DIM, H_DIM,
                     kt * 64, nt * 256,
                     w2t + ((size_t)((e2 * 4 + nt) * 64 + kt)) * 16384,
                     tid);
    return;
  }

  int* tok = (int*)(smem + 65536);
  int lin = item;
  lin = (lin & 7) * (G1_ITEMS / 8) + (lin >> 3);  // bijective XCD swizzle (640%8==0)
  const int ti = lin % NT, ct = lin / NT;
  const int mEnc = tmap[ti];
  if (mEnc < 0) return;
  const int e = mEnc >> 16, rt = mEnc & 0xffff;
  const int cnt = counts[e];
  const int lane = tid & 63, wv = tid >> 6;
  if (tid < 256) {
    int s = rt * 256 + tid;
    if (s >= cnt) s = cnt - 1;
    tok[tid] = entry_token[e * T_TOK + s];
  }
  __syncthreads();
  const int r0 = ((tid >> 7) << 4) + ((tid >> 2) & 15);                       // [0,64)
  const int kb = (((tid >> 6) & 1) << 5) + (((tid & 3) << 3) ^ (((tid >> 5) & 1) << 4));
  const char* xbb = (const char*)xb;
  const char* pa0s0 = xbb + (size_t)tok[r0]       * 2048 + kb * 2;
  const char* pa0s1 = xbb + (size_t)tok[64 + r0]  * 2048 + kb * 2;
  const char* pa1s0 = xbb + (size_t)tok[128 + r0] * 2048 + kb * 2;
  const char* pa1s1 = xbb + (size_t)tok[192 + r0] * 2048 + kb * 2;
  const char* w1e = (const char*)w1t + ((size_t)(e * 16 + ct) * 16) * 32768;
  const char* pb0s0 = w1e + tid * 16;
  const char* pb0s1 = w1e + 8192 + tid * 16;
  const char* pb1s0 = w1e + 16384 + tid * 16;
  const char* pb1s1 = w1e + 24576 + tid * 16;
  const int amfrag = (wv >> 2) * 4;
  const int bnfrag = (wv & 3) * 2;
  const int mb0 = (wv >> 2) * 64, nb0 = (wv & 3) * 32;
  const int lane_off = (lane & 15) * 64 + ((((lane >> 4) << 3) ^ (((lane >> 3) & 1) << 4)) << 1);
  ACC_INIT()
  KLOOP_SB(16)
  const int rb = hoff[e] + rt * 256;
  const float* b1e = b1 + (size_t)e * DFF_D;
#define EPI1(ACC, A_, B_) \
  _Pragma("unroll") for (int mi = 0; mi < 4; ++mi) \
  _Pragma("unroll") for (int ni = 0; ni < 2; ++ni) { \
    const int n = ct * 256 + (B_) * 128 + nb0 + ni * 16 + (lane & 15); \
    const float bias = b1e[n]; \
    _Pragma("unroll") for (int q = 0; q < 4; ++q) { \
      const int m = (A_) * 128 + mb0 + mi * 16 + (lane >> 4) * 4 + q; \
      float v = ACC[mi][ni][q] + bias; v = v > 0.f ? v : 0.f; \
      h[(size_t)(rb + m) * DFF_D + n] = f2bf(v); \
    } }
  EPI1(q00, 0, 0) EPI1(q01, 0, 1) EPI1(q10, 1, 0) EPI1(q11, 1, 1)
#undef EPI1
}

// ---------------- GEMM2: yp[part] = gate * (h @ w2^T (+ b2)) , split-K=3 ----------------
__global__ __launch_bounds__(512, 4) void gemm2_kernel(
    const unsigned short* __restrict__ h,     // [HROWS][4096]
    const unsigned short* __restrict__ w2t,   // TILED [E][4 nt][64 kt][32KB]
    const float* __restrict__ b2,
    const int* __restrict__ hoff, const int* __restrict__ tmap,
    const float* __restrict__ entry_gate,
    unsigned short* __restrict__ yp)          // [3][HROWS][1024]
{
  extern __shared__ char smem[];
  char* sA = smem;
  char* sB = smem + 32768;
  int lin = (blockIdx.z * NT + blockIdx.y) * 4 + blockIdx.x;  // nwg = 480
  lin = (lin & 7) * (3 * NT * 4 / 8) + (lin >> 3);            // bijective
  const int ct = lin & 3;
  const int g = lin >> 2;
  const int ti = g % NT, part = g / NT;
  const int mEnc = tmap[ti];
  if (mEnc < 0) return;
  const int e = mEnc >> 16, rt = mEnc & 0xffff;
  int S, KT;
  if (part == 0)      { S = 0;  KT = 22; }
  else if (part == 1) { S = 22; KT = 21; }
  else                { S = 43; KT = 21; }
  const int tid = threadIdx.x, lane = tid & 63, wv = tid >> 6;
  const int rb = hoff[e] + rt * 256;
  const int r0 = ((tid >> 7) << 4) + ((tid >> 2) & 15);
  const int kb = (((tid >> 6) & 1) << 5) + (((tid & 3) << 3) ^ (((tid >> 5) & 1) << 4));
  const char* hb = (const char*)h + (size_t)S * 128;
  const char* pa0s0 = hb + (size_t)(rb + r0)       * 8192 + kb * 2;
  const char* pa0s1 = hb + (size_t)(rb + 64 + r0)  * 8192 + kb * 2;
  const char* pa1s0 = hb + (size_t)(rb + 128 + r0) * 8192 + kb * 2;
  const char* pa1s1 = hb + (size_t)(rb + 192 + r0) * 8192 + kb * 2;
  const char* w2e = (const char*)w2t + ((size_t)((e * 4 + ct) * 64 + S)) * 32768;
  const char* pb0s0 = w2e + tid * 16;
  const char* pb0s1 = w2e + 8192 + tid * 16;
  const char* pb1s0 = w2e + 16384 + tid * 16;
  const char* pb1s1 = w2e + 24576 + tid * 16;
  const int amfrag = (wv >> 2) * 4;
  const int bnfrag = (wv & 3) * 2;
  const int mb0 = (wv >> 2) * 64, nb0 = (wv & 3) * 32;
  const int lane_off = (lane & 15) * 64 + ((((lane >> 4) << 3) ^ (((lane >> 3) & 1) << 4)) << 1);
  ACC_INIT()
  KLOOP_SB(KT)
  unsigned short* yout = yp + (size_t)part * HROWS * H_DIM;
  const float* b2e = b2 + (size_t)e * H_DIM;
  const float* ge = entry_gate + (size_t)e * T_TOK + rt * 256;
#define EPI2(ACC, A_, B_) \
  _Pragma("unroll") for (int mi = 0; mi < 4; ++mi) \
  _Pragma("unroll") for (int ni = 0; ni < 2; ++ni) { \
    const int n = ct * 256 + (B_) * 128 + nb0 + ni * 16 + (lane & 15); \
    const float bias = (part == 0) ? b2e[n] : 0.f; \
    _Pragma("unroll") for (int q = 0; q < 4; ++q) { \
      const int m = (A_) * 128 + mb0 + mi * 16 + (lane >> 4) * 4 + q; \
      const float gate = ge[m];  /* pad rows: garbage, never combined */ \
      float v = (ACC[mi][ni][q] + bias) * gate; \
      yout[(size_t)(rb + m) * H_DIM + n] = f2bf(v); \
    } }
  EPI2(q00, 0, 0) EPI2(q01, 0, 1) EPI2(q10, 1, 0) EPI2(q11, 1, 1)
#undef EPI2
}

// ---------------- combine: out[t] = sum_{p,k} yp[p][row(t,k)] ----------------
__global__ void combine_kernel(const unsigned short* __restrict__ yp,
                               const int* __restrict__ ids, const int* __restrict__ slots,
                               const int* __restrict__ hoff, float* __restrict__ out) {
  const int t = blockIdx.x, tid = threadIdx.x;
  const int r0 = hoff[ids[t * 2]] + slots[t * 2];
  const int r1 = hoff[ids[t * 2 + 1]] + slots[t * 2 + 1];
  const int c = tid * 4;
  float4 o = {0.f, 0.f, 0.f, 0.f};
#pragma unroll
  for (int p = 0; p < 3; ++p) {
    const unsigned short* pl = yp + (size_t)p * HROWS * H_DIM;
    ushort4 a = *(const ushort4*)&pl[(size_t)r0 * H_DIM + c];
    ushort4 b = *(const ushort4*)&pl[(size_t)r1 * H_DIM + c];
    o.x += bf2f(a.x) + bf2f(b.x);
    o.y += bf2f(a.y) + bf2f(b.y);
    o.z += bf2f(a.z) + bf2f(b.z);
    o.w += bf2f(a.w) + bf2f(b.w);
  }
  *(float4*)&out[(size_t)t * H_DIM + c] = o;
}

__global__ void ws_fail_kernel(float* out) {
  if (threadIdx.x == 0 && blockIdx.x == 0) out[0] = -12345.0f;
}

// ---------------- workspace layout (bytes) ----------------
#define XB_OFF    ((size_t)0)           // 8,388,608   (dead after gemm1)
#define W1T_OFF   ((size_t)8388608)     // 67,108,864  (dead after gemm1)
#define YP_OFF    ((size_t)0)           // 3*10240*1024*2 = 62,914,560 (aliases xb+w1t)
#define W2T_OFF   ((size_t)75497472)    // 67,108,864
#define H_OFF     ((size_t)142606336)   // 83,886,080
#define TMAP_OFF  ((size_t)226492416)   // 256
#define ET_OFF    ((size_t)226492672)   // 131,072
#define EG_OFF    ((size_t)226623744)   // 131,072
#define IDS_OFF   ((size_t)226754816)   // 32,768
#define SLOT_OFF  ((size_t)226787584)   // 32,768
#define CNT_OFF   ((size_t)226820352)   // 64
#define HOFF_OFF  ((size_t)226820416)   // 64
#define PART_OFF  ((size_t)226820480)   // 98,304
#define BCNT_OFF  ((size_t)226918784)   // 16,384
#define LOCS_OFF  ((size_t)226935168)   // 32,768
#define TOKG_OFF  ((size_t)226967936)   // 32,768
#define WS_NEED   ((size_t)227000704)

extern "C" void kernel_launch(void* const* d_in, const int* in_sizes, int n_in,
                              void* d_out, int out_size, void* d_ws, size_t ws_size,
                              hipStream_t stream) {
  const float* x  = (const float*)d_in[0];
  const float* gw = (const float*)d_in[1];
  const float* gb = (const float*)d_in[2];
  const float* w1 = (const float*)d_in[3];
  const float* b1 = (const float*)d_in[4];
  const float* w2 = (const float*)d_in[5];
  const float* b2 = (const float*)d_in[6];
  float* out = (float*)d_out;
  char* ws = (char*)d_ws;

  if (ws_size < WS_NEED) {
    ws_fail_kernel<<<1, 64, 0, stream>>>(out);
    return;
  }

  unsigned short* xb  = (unsigned short*)(ws + XB_OFF);
  unsigned short* w1t = (unsigned short*)(ws + W1T_OFF);
  unsigned short* yp  = (unsigned short*)(ws + YP_OFF);
  unsigned short* w2t = (unsigned short*)(ws + W2T_OFF);
  unsigned short* h   = (unsigned short*)(ws + H_OFF);
  int*   tmap  = (int*)(ws + TMAP_OFF);
  int*   etok  = (int*)(ws + ET_OFF);
  float* egate = (float*)(ws + EG_OFF);
  int*   ids   = (int*)(ws + IDS_OFF);
  int*   slots = (int*)(ws + SLOT_OFF);
  int*   counts= (int*)(ws + CNT_OFF);
  int*   hoff  = (int*)(ws + HOFF_OFF);
  float* parts = (float*)(ws + PART_OFF);
  int*   bcnt  = (int*)(ws + BCNT_OFF);
  int*   locs  = (int*)(ws + LOCS_OFF);
  float* tokg  = (float*)(ws + TOKG_OFF);

  gate_tr1_kernel<<<GATE_BLKS + TR1_ITEMS, 512, 33280, stream>>>(
      x, gw, gb, ids, locs, tokg, bcnt, parts, xb, w1, w1t);
  meta_kernel<<<1, 1024, 0, stream>>>(bcnt, ids, locs, tokg, parts,
                                      counts, hoff, tmap, etok, egate, slots,
                                      out + (size_t)T_TOK * H_DIM);
  gemm1_kernel<<<G1_ITEMS + TR2_ITEMS, 512, 66560, stream>>>(
      xb, w1t, b1, counts, hoff, tmap, etok, h, w2, w2t);
  gemm2_kernel<<<dim3(4, NT, 3), 512, 65536, stream>>>(h, w2t, b2, hoff, tmap, egate, yp);
  combine_kernel<<<4096, 256, 0, stream>>>(yp, ids, slots, hoff, out);
}

// Round 17
// 347.724 us; speedup vs baseline: 4.0088x; 4.0088x over previous
//
#include <hip/hip_runtime.h>
#include <stdint.h>

#define T_TOK 4096
#define H_DIM 1024
#define E_EXP 8
#define DFF_D 4096
#define HROWS 10240
#define NT 40
#define G1_ITEMS 640          // 16 ct * NT
#define TR2_ITEMS 2048        // w2: 8 e * 4 nt * 64 kt
#define GATE_BLKS 512
#define TR1_ITEMS 2048        // w1: 8 e * 16 nt * 16 kt

typedef __attribute__((ext_vector_type(4))) float f32x4;
typedef __attribute__((ext_vector_type(8))) __bf16 bf16x8;

static __device__ __forceinline__ unsigned short f2bf(float f) {
  union { float f; unsigned u; } v; v.f = f;
  unsigned r = v.u + 0x7FFFu + ((v.u >> 16) & 1u);
  return (unsigned short)(r >> 16);
}
static __device__ __forceinline__ float bf2f(unsigned short u) {
  union { unsigned u; float f; } v; v.u = ((unsigned)u) << 16; return v.f;
}
static __device__ __forceinline__ void load_lds16(const void* g, void* l) {
  __builtin_amdgcn_global_load_lds(
      (const __attribute__((address_space(1))) unsigned int*)g,
      (__attribute__((address_space(3))) unsigned int*)l, 16, 0, 0);
}

#define MEMF() asm volatile("" ::: "memory")
#define BAR()  { MEMF(); __builtin_amdgcn_s_barrier(); MEMF(); }
#define VM0()  asm volatile("s_waitcnt vmcnt(0)" ::: "memory")
#define SP1()  __builtin_amdgcn_s_setprio(1)
#define SP0()  __builtin_amdgcn_s_setprio(0)

// ---- R11-verified: transpose 64x256 src tile -> one 32KB consumption-order B tile ----
static __device__ __forceinline__ void tr_tile_to_tiled(
    unsigned short* __restrict__ tile16,         // LDS [64][260] ushort
    const float* __restrict__ src, int src_ld,
    int r0, int c0,                              // src row(k)/col(n) base
    unsigned short* __restrict__ tile_out,       // 32KB block
    int tid) {
  const int w = tid >> 6, lane = tid & 63;
#pragma unroll
  for (int i = 0; i < 8; ++i) {
    const int row = w * 8 + i;
    float4 v = *(const float4*)&src[(size_t)(r0 + row) * src_ld + c0 + 4 * lane];
    ushort4 o;
    o.x = f2bf(v.x); o.y = f2bf(v.y); o.z = f2bf(v.z); o.w = f2bf(v.w);
    *(ushort4*)&tile16[row * 260 + 4 * lane] = o;
  }
  __syncthreads();
  const int r0t = ((tid >> 7) << 4) + ((tid >> 2) & 15);
  const int kbt = (((tid >> 6) & 1) << 5) + (((tid & 3) << 3) ^ (((tid >> 5) & 1) << 4));
#pragma unroll
  for (int half = 0; half < 2; ++half)
#pragma unroll
    for (int j = 0; j < 2; ++j) {
      const int c = half * 128 + 64 * j + r0t;
      unsigned ow[4];
#pragma unroll
      for (int p = 0; p < 4; ++p)
        ow[p] = (unsigned)tile16[(kbt + 2 * p) * 260 + c]
              | ((unsigned)tile16[(kbt + 2 * p + 1) * 260 + c] << 16);
      *(uint4*)((char*)tile_out + half * 16384 + j * 8192 + tid * 16) = *(uint4*)ow;
    }
}

// ---------------- fused: gate (atomic-free) + w1 transpose ----------------
__global__ __launch_bounds__(512) void gate_tr1_kernel(
    const float* __restrict__ x, const float* __restrict__ gw,
    const float* __restrict__ gb,
    int* __restrict__ ids, int* __restrict__ locs, float* __restrict__ tokg,
    int* __restrict__ bcnt, float* __restrict__ partials,
    unsigned short* __restrict__ xb,
    const float* __restrict__ w1, unsigned short* __restrict__ w1t) {
  extern __shared__ char smem[];
  const int tid = threadIdx.x;
  const int blk = blockIdx.x;

  if (blk >= GATE_BLKS) {
    const int j = blk - GATE_BLKS;               // [0, 2048)
    const int e2 = j >> 8;
    const int jj = j & 255;
    const int nt = jj >> 4, kt = jj & 15;
    tr_tile_to_tiled((unsigned short*)smem,
                     w1 + (size_t)e2 * H_DIM * DFF_D, DFF_D,
                     kt * 64, nt * 256,
                     w1t + ((size_t)((e2 * 16 + nt) * 16 + kt)) * 16384,
                     tid);
    return;
  }

  // ---- gate (atomic-free, deterministic intra-block ranking) ----
  float (*probs_lds)[8] = (float(*)[8])smem;              // [8][8]
  int   (*topi_lds)[2]  = (int(*)[2])(smem + 256);        // [8][2]
  int*  locs_lds        = (int*)(smem + 320);             // [16]
  int*  cnt_lds         = (int*)(smem + 384);             // [8]
  const int lane = tid & 63, tl = tid >> 6;
  const int token = blk * 8 + tl;
  float a[8];
#pragma unroll
  for (int e = 0; e < 8; ++e) a[e] = 0.f;
#pragma unroll
  for (int i = 0; i < 4; ++i) {
    const int k4 = i * 256 + lane * 4;
    float4 xv4 = *(const float4*)&x[(size_t)token * H_DIM + k4];
    ushort4 xo;
    xo.x = f2bf(xv4.x); xo.y = f2bf(xv4.y); xo.z = f2bf(xv4.z); xo.w = f2bf(xv4.w);
    *(ushort4*)&xb[(size_t)token * H_DIM + k4] = xo;
#pragma unroll
    for (int j = 0; j < 4; ++j) {
      const float xv = ((const float*)&xv4)[j];
      const float4* g = (const float4*)&gw[(size_t)(k4 + j) * 8];
      float4 g0 = g[0], g1 = g[1];
      a[0] += xv * g0.x; a[1] += xv * g0.y; a[2] += xv * g0.z; a[3] += xv * g0.w;
      a[4] += xv * g1.x; a[5] += xv * g1.y; a[6] += xv * g1.z; a[7] += xv * g1.w;
    }
  }
  for (int m = 32; m >= 1; m >>= 1) {
#pragma unroll
    for (int e = 0; e < 8; ++e) a[e] += __shfl_xor(a[e], m);
  }
  if (lane == 0) {
    float lg[8], p[8];
    float mx = -1e30f;
#pragma unroll
    for (int e = 0; e < 8; ++e) { lg[e] = a[e] + gb[e]; mx = lg[e] > mx ? lg[e] : mx; }
    float s = 0.f;
#pragma unroll
    for (int e = 0; e < 8; ++e) { p[e] = expf(lg[e] - mx); s += p[e]; }
    float inv = 1.f / s;
#pragma unroll
    for (int e = 0; e < 8; ++e) p[e] *= inv;
    int i0 = 0;
#pragma unroll
    for (int e = 1; e < 8; ++e) if (p[e] > p[i0]) i0 = e;
    int i1 = (i0 == 0) ? 1 : 0;
#pragma unroll
    for (int e = 0; e < 8; ++e) if (e != i0 && p[e] > p[i1]) i1 = e;
#pragma unroll
    for (int e = 0; e < 8; ++e) probs_lds[tl][e] = p[e];
    topi_lds[tl][0] = i0; topi_lds[tl][1] = i1;
  }
  __syncthreads();
  if (tid == 0) {
    int run[8];
#pragma unroll
    for (int e = 0; e < 8; ++e) run[e] = 0;
    for (int q = 0; q < 16; ++q) {
      const int e = topi_lds[q >> 1][q & 1];
      locs_lds[q] = run[e]++;
    }
#pragma unroll
    for (int e = 0; e < 8; ++e) cnt_lds[e] = run[e];
  }
  __syncthreads();
  if (tid < 16) {
    const int tt = tid >> 1, c = tid & 1;
    const int t2 = blk * 8 + tt;
    const int e = topi_lds[tt][c];
    ids[t2 * 2 + c]  = e;
    locs[t2 * 2 + c] = locs_lds[tid];
    tokg[t2 * 2 + c] = probs_lds[tt][e];
  }
  if (tid >= 16 && tid < 24) bcnt[blk * 8 + (tid - 16)] = cnt_lds[tid - 16];
  if (tid < 24) {
    int e = tid & 7, which = tid >> 3;
    float s = 0.f;
#pragma unroll
    for (int tt = 0; tt < 8; ++tt) {
      float pv = probs_lds[tt][e];
      bool m = (topi_lds[tt][0] == e) || (topi_lds[tt][1] == e);
      if (which == 0) s += pv;
      else if (which == 1) s += m ? 1.f : 0.f;
      else s += m ? pv : 0.f;
    }
    partials[blk * 24 + tid] = s;
  }
}

// ---------------- meta: scan + scatter + offsets/tilemap + aux ----------------
__global__ __launch_bounds__(1024) void meta_kernel(
    const int* __restrict__ bcnt, const int* __restrict__ ids,
    const int* __restrict__ locs, const float* __restrict__ tokg,
    const float* __restrict__ partials,
    int* __restrict__ counts, int* __restrict__ hoff, int* __restrict__ tmap,
    int* __restrict__ entry_token, float* __restrict__ entry_gate,
    int* __restrict__ slots, float* __restrict__ out_aux) {
  __shared__ int sc[8][513];
  __shared__ float red[24][33];
  const int tid = threadIdx.x;
#pragma unroll
  for (int j = 0; j < 4; ++j) {
    const int idx = tid + j * 1024;
    const int e = idx >> 9, b = idx & 511;
    sc[e][b] = bcnt[b * 8 + e];
  }
  __syncthreads();
  for (int off = 1; off < 512; off <<= 1) {
    int v[4];
#pragma unroll
    for (int j = 0; j < 4; ++j) {
      const int idx = tid + j * 1024;
      const int e = idx >> 9, b = idx & 511;
      v[j] = sc[e][b] + (b >= off ? sc[e][b - off] : 0);
    }
    __syncthreads();
#pragma unroll
    for (int j = 0; j < 4; ++j) {
      const int idx = tid + j * 1024;
      sc[idx >> 9][idx & 511] = v[j];
    }
    __syncthreads();
  }
  if (tid == 0) {
    int o = 0, nt = 0;
    for (int e = 0; e < E_EXP; ++e) {
      const int ce = sc[e][511];
      counts[e] = ce;
      hoff[e] = o;
      int rtc = (ce + 255) >> 8;
      o += rtc << 8;
      for (int rt = 0; rt < rtc; ++rt) tmap[nt++] = (e << 16) | rt;
    }
    hoff[E_EXP] = o;
    for (; nt < NT; ++nt) tmap[nt] = -1;
  }
  __syncthreads();
#pragma unroll
  for (int j = 0; j < 8; ++j) {
    const int idx = tid + j * 1024;
    const int t = idx >> 1, c = idx & 1, b = t >> 3;
    const int e = ids[t * 2 + c];
    const int slot = sc[e][b] - bcnt[b * 8 + e] + locs[t * 2 + c];
    entry_token[e * T_TOK + slot] = t;
    entry_gate[e * T_TOK + slot] = tokg[t * 2 + c];
    slots[t * 2 + c] = slot;
  }
  const int c = tid & 31, g = tid >> 5;
  if (c < 24) {
    float s = 0.f;
    for (int j = 0; j < 16; ++j) s += partials[(size_t)(g + j * 32) * 24 + c];
    red[c][g] = s;
  }
  __syncthreads();
  if (tid < 24) {
    float t2 = 0.f;
#pragma unroll
    for (int g2 = 0; g2 < 32; ++g2) t2 += red[tid][g2];
    red[tid][32] = t2;
  }
  __syncthreads();
  if (tid == 0) {
    float mean = 0.f;
    for (int e = 0; e < 8; ++e) mean += red[e][32];
    mean *= 0.125f;
    float var = 0.f;
    for (int e = 0; e < 8; ++e) { float d = red[e][32] - mean; var += d * d; }
    var *= (1.f / 7.f);
    float il = var * (1.f / 64.f);
    float lb = 0.f;
    for (int e = 0; e < 8; ++e)
      lb += (red[8 + e][32] / (float)T_TOK) * (red[16 + e][32] / (float)T_TOK);
    lb *= 8.f;
    out_aux[0] = il + lb;
  }
}

// ======== 256x256x64 grouped-GEMM, SINGLE-buffered LDS (64KB) -> 2 blocks/CU ========
// m97-style loop: stage-all -> vmcnt(0) -> barrier -> compute (reg reuse) -> barrier.
// Latency hidden by co-resident block (TLP).  launch_bounds(512,2) -> 128 VGPR cap.
#define STG_A0s(m_) { char* lb_ = sA + wv*1024; \
  load_lds16(pa0s0 + (size_t)(m_)*128, lb_); load_lds16(pa0s1 + (size_t)(m_)*128, lb_ + 8192); }
#define STG_A1s(m_) { char* lb_ = sA + 16384 + wv*1024; \
  load_lds16(pa1s0 + (size_t)(m_)*128, lb_); load_lds16(pa1s1 + (size_t)(m_)*128, lb_ + 8192); }
#define STG_B0s(m_) { char* lb_ = sB + wv*1024; \
  load_lds16(pb0s0 + (size_t)(m_)*32768, lb_); load_lds16(pb0s1 + (size_t)(m_)*32768, lb_ + 8192); }
#define STG_B1s(m_) { char* lb_ = sB + 16384 + wv*1024; \
  load_lds16(pb1s0 + (size_t)(m_)*32768, lb_); load_lds16(pb1s1 + (size_t)(m_)*32768, lb_ + 8192); }

#define LDA8(DST, AD) \
  _Pragma("unroll") for (int mi = 0; mi < 4; ++mi) \
  _Pragma("unroll") for (int kk = 0; kk < 2; ++kk) \
    DST[mi][kk] = *(const bf16x8*)((AD) + (amfrag + mi) * 2048 + kk * 1024 + lane_off);
#define LDB4(DST, BD) \
  _Pragma("unroll") for (int ni = 0; ni < 2; ++ni) \
  _Pragma("unroll") for (int kk = 0; kk < 2; ++kk) \
    DST[ni][kk] = *(const bf16x8*)((BD) + (bnfrag + ni) * 2048 + kk * 1024 + lane_off);
#define MF16(ACC, AF, BF) \
  _Pragma("unroll") for (int mi = 0; mi < 4; ++mi) \
  _Pragma("unroll") for (int ni = 0; ni < 2; ++ni) \
  _Pragma("unroll") for (int kk = 0; kk < 2; ++kk) \
    ACC[mi][ni] = __builtin_amdgcn_mfma_f32_16x16x32_bf16(AF[mi][kk], BF[ni][kk], ACC[mi][ni], 0, 0, 0);

#define ACC_INIT() \
  f32x4 q00[4][2], q01[4][2], q10[4][2], q11[4][2]; \
  _Pragma("unroll") for (int mi = 0; mi < 4; ++mi) \
  _Pragma("unroll") for (int ni = 0; ni < 2; ++ni) { \
    q00[mi][ni] = (f32x4){0.f,0.f,0.f,0.f}; q01[mi][ni] = (f32x4){0.f,0.f,0.f,0.f}; \
    q10[mi][ni] = (f32x4){0.f,0.f,0.f,0.f}; q11[mi][ni] = (f32x4){0.f,0.f,0.f,0.f}; }

#define KLOOP_SB(KT) \
  for (int k = 0; k < (KT); ++k) { \
    STG_A0s(k); STG_A1s(k); STG_B0s(k); STG_B1s(k); \
    VM0(); \
    BAR(); \
    bf16x8 alo[4][2], ahi[4][2], blo[2][2], bhi[2][2]; \
    LDA8(alo, sA); LDB4(blo, sB); \
    SP1(); MF16(q00, alo, blo); SP0(); \
    LDB4(bhi, sB + 16384); \
    SP1(); MF16(q01, alo, bhi); SP0(); \
    LDA8(ahi, sA + 16384); \
    SP1(); MF16(q10, ahi, blo); SP0(); \
    SP1(); MF16(q11, ahi, bhi); SP0(); \
    BAR(); \
  }

// ---------------- GEMM1 (+ fused w2 transpose items in tail blocks) ----------------
__global__ __launch_bounds__(512, 2) void gemm1_kernel(
    const unsigned short* __restrict__ xb,    // [T][1024]
    const unsigned short* __restrict__ w1t,   // TILED [E][16 nt][16 kt][32KB]
    const float* __restrict__ b1,
    const int* __restrict__ counts, const int* __restrict__ hoff,
    const int* __restrict__ tmap, const int* __restrict__ entry_token,
    unsigned short* __restrict__ h,           // [HROWS][4096]
    const float* __restrict__ w2,             // [E][4096][1024] f32
    unsigned short* __restrict__ w2t)         // TILED [E][4 nt][64 kt][32KB]
{
  extern __shared__ char smem[];
  char* sA = smem;
  char* sB = smem + 32768;
  const int tid = threadIdx.x;
  const int item = blockIdx.x;

  if (item >= G1_ITEMS) {
    const int j = item - G1_ITEMS;            // [0, 2048)
    const int e2 = j >> 8;
    const int jj = j & 255;
    const int nt = jj >> 6, kt = jj & 63;
    tr_tile_to_tiled((unsigned short*)smem,
                     w2 + (size_t)e2 * DFF_D * H_DIM, H_DIM,
                     kt * 64, nt * 256,
                     w2t + ((size_t)((e2 * 4 + nt) * 64 + kt)) * 16384,
                     tid);
    return;
  }

  int* tok = (int*)(smem + 65536);
  int lin = item;
  lin = (lin & 7) * (G1_ITEMS / 8) + (lin >> 3);  // bijective XCD swizzle (640%8==0)
  const int ti = lin % NT, ct = lin / NT;
  const int mEnc = tmap[ti];
  if (mEnc < 0) return;
  const int e = mEnc >> 16, rt = mEnc & 0xffff;
  const int cnt = counts[e];
  const int lane = tid & 63, wv = tid >> 6;
  if (tid < 256) {
    int s = rt * 256 + tid;
    if (s >= cnt) s = cnt - 1;
    tok[tid] = entry_token[e * T_TOK + s];
  }
  __syncthreads();
  const int r0 = ((tid >> 7) << 4) + ((tid >> 2) & 15);                       // [0,64)
  const int kb = (((tid >> 6) & 1) << 5) + (((tid & 3) << 3) ^ (((tid >> 5) & 1) << 4));
  const char* xbb = (const char*)xb;
  const char* pa0s0 = xbb + (size_t)tok[r0]       * 2048 + kb * 2;
  const char* pa0s1 = xbb + (size_t)tok[64 + r0]  * 2048 + kb * 2;
  const char* pa1s0 = xbb + (size_t)tok[128 + r0] * 2048 + kb * 2;
  const char* pa1s1 = xbb + (size_t)tok[192 + r0] * 2048 + kb * 2;
  const char* w1e = (const char*)w1t + ((size_t)(e * 16 + ct) * 16) * 32768;
  const char* pb0s0 = w1e + tid * 16;
  const char* pb0s1 = w1e + 8192 + tid * 16;
  const char* pb1s0 = w1e + 16384 + tid * 16;
  const char* pb1s1 = w1e + 24576 + tid * 16;
  const int amfrag = (wv >> 2) * 4;
  const int bnfrag = (wv & 3) * 2;
  const int mb0 = (wv >> 2) * 64, nb0 = (wv & 3) * 32;
  const int lane_off = (lane & 15) * 64 + ((((lane >> 4) << 3) ^ (((lane >> 3) & 1) << 4)) << 1);
  ACC_INIT()
  KLOOP_SB(16)
  const int rb = hoff[e] + rt * 256;
  const float* b1e = b1 + (size_t)e * DFF_D;
#define EPI1(ACC, A_, B_) \
  _Pragma("unroll") for (int mi = 0; mi < 4; ++mi) \
  _Pragma("unroll") for (int ni = 0; ni < 2; ++ni) { \
    const int n = ct * 256 + (B_) * 128 + nb0 + ni * 16 + (lane & 15); \
    const float bias = b1e[n]; \
    _Pragma("unroll") for (int q = 0; q < 4; ++q) { \
      const int m = (A_) * 128 + mb0 + mi * 16 + (lane >> 4) * 4 + q; \
      float v = ACC[mi][ni][q] + bias; v = v > 0.f ? v : 0.f; \
      h[(size_t)(rb + m) * DFF_D + n] = f2bf(v); \
    } }
  EPI1(q00, 0, 0) EPI1(q01, 0, 1) EPI1(q10, 1, 0) EPI1(q11, 1, 1)
#undef EPI1
}

// ---------------- GEMM2: yp[part] = gate * (h @ w2^T (+ b2)) , split-K=3 ----------------
__global__ __launch_bounds__(512, 2) void gemm2_kernel(
    const unsigned short* __restrict__ h,     // [HROWS][4096]
    const unsigned short* __restrict__ w2t,   // TILED [E][4 nt][64 kt][32KB]
    const float* __restrict__ b2,
    const int* __restrict__ hoff, const int* __restrict__ tmap,
    const float* __restrict__ entry_gate,
    unsigned short* __restrict__ yp)          // [3][HROWS][1024]
{
  extern __shared__ char smem[];
  char* sA = smem;
  char* sB = smem + 32768;
  int lin = (blockIdx.z * NT + blockIdx.y) * 4 + blockIdx.x;  // nwg = 480
  lin = (lin & 7) * (3 * NT * 4 / 8) + (lin >> 3);            // bijective
  const int ct = lin & 3;
  const int g = lin >> 2;
  const int ti = g % NT, part = g / NT;
  const int mEnc = tmap[ti];
  if (mEnc < 0) return;
  const int e = mEnc >> 16, rt = mEnc & 0xffff;
  int S, KT;
  if (part == 0)      { S = 0;  KT = 22; }
  else if (part == 1) { S = 22; KT = 21; }
  else                { S = 43; KT = 21; }
  const int tid = threadIdx.x, lane = tid & 63, wv = tid >> 6;
  const int rb = hoff[e] + rt * 256;
  const int r0 = ((tid >> 7) << 4) + ((tid >> 2) & 15);
  const int kb = (((tid >> 6) & 1) << 5) + (((tid & 3) << 3) ^ (((tid >> 5) & 1) << 4));
  const char* hb = (const char*)h + (size_t)S * 128;
  const char* pa0s0 = hb + (size_t)(rb + r0)       * 8192 + kb * 2;
  const char* pa0s1 = hb + (size_t)(rb + 64 + r0)  * 8192 + kb * 2;
  const char* pa1s0 = hb + (size_t)(rb + 128 + r0) * 8192 + kb * 2;
  const char* pa1s1 = hb + (size_t)(rb + 192 + r0) * 8192 + kb * 2;
  const char* w2e = (const char*)w2t + ((size_t)((e * 4 + ct) * 64 + S)) * 32768;
  const char* pb0s0 = w2e + tid * 16;
  const char* pb0s1 = w2e + 8192 + tid * 16;
  const char* pb1s0 = w2e + 16384 + tid * 16;
  const char* pb1s1 = w2e + 24576 + tid * 16;
  const int amfrag = (wv >> 2) * 4;
  const int bnfrag = (wv & 3) * 2;
  const int mb0 = (wv >> 2) * 64, nb0 = (wv & 3) * 32;
  const int lane_off = (lane & 15) * 64 + ((((lane >> 4) << 3) ^ (((lane >> 3) & 1) << 4)) << 1);
  ACC_INIT()
  KLOOP_SB(KT)
  unsigned short* yout = yp + (size_t)part * HROWS * H_DIM;
  const float* b2e = b2 + (size_t)e * H_DIM;
  const float* ge = entry_gate + (size_t)e * T_TOK + rt * 256;
#define EPI2(ACC, A_, B_) \
  _Pragma("unroll") for (int mi = 0; mi < 4; ++mi) \
  _Pragma("unroll") for (int ni = 0; ni < 2; ++ni) { \
    const int n = ct * 256 + (B_) * 128 + nb0 + ni * 16 + (lane & 15); \
    const float bias = (part == 0) ? b2e[n] : 0.f; \
    _Pragma("unroll") for (int q = 0; q < 4; ++q) { \
      const int m = (A_) * 128 + mb0 + mi * 16 + (lane >> 4) * 4 + q; \
      const float gate = ge[m];  /* pad rows: garbage, never combined */ \
      float v = (ACC[mi][ni][q] + bias) * gate; \
      yout[(size_t)(rb + m) * H_DIM + n] = f2bf(v); \
    } }
  EPI2(q00, 0, 0) EPI2(q01, 0, 1) EPI2(q10, 1, 0) EPI2(q11, 1, 1)
#undef EPI2
}

// ---------------- combine: out[t] = sum_{p,k} yp[p][row(t,k)] ----------------
__global__ void combine_kernel(const unsigned short* __restrict__ yp,
                               const int* __restrict__ ids, const int* __restrict__ slots,
                               const int* __restrict__ hoff, float* __restrict__ out) {
  const int t = blockIdx.x, tid = threadIdx.x;
  const int r0 = hoff[ids[t * 2]] + slots[t * 2];
  const int r1 = hoff[ids[t * 2 + 1]] + slots[t * 2 + 1];
  const int c = tid * 4;
  float4 o = {0.f, 0.f, 0.f, 0.f};
#pragma unroll
  for (int p = 0; p < 3; ++p) {
    const unsigned short* pl = yp + (size_t)p * HROWS * H_DIM;
    ushort4 a = *(const ushort4*)&pl[(size_t)r0 * H_DIM + c];
    ushort4 b = *(const ushort4*)&pl[(size_t)r1 * H_DIM + c];
    o.x += bf2f(a.x) + bf2f(b.x);
    o.y += bf2f(a.y) + bf2f(b.y);
    o.z += bf2f(a.z) + bf2f(b.z);
    o.w += bf2f(a.w) + bf2f(b.w);
  }
  *(float4*)&out[(size_t)t * H_DIM + c] = o;
}

__global__ void ws_fail_kernel(float* out) {
  if (threadIdx.x == 0 && blockIdx.x == 0) out[0] = -12345.0f;
}

// ---------------- workspace layout (bytes) ----------------
#define XB_OFF    ((size_t)0)           // 8,388,608   (dead after gemm1)
#define W1T_OFF   ((size_t)8388608)     // 67,108,864  (dead after gemm1)
#define YP_OFF    ((size_t)0)           // 3*10240*1024*2 = 62,914,560 (aliases xb+w1t)
#define W2T_OFF   ((size_t)75497472)    // 67,108,864
#define H_OFF     ((size_t)142606336)   // 83,886,080
#define TMAP_OFF  ((size_t)226492416)   // 256
#define ET_OFF    ((size_t)226492672)   // 131,072
#define EG_OFF    ((size_t)226623744)   // 131,072
#define IDS_OFF   ((size_t)226754816)   // 32,768
#define SLOT_OFF  ((size_t)226787584)   // 32,768
#define CNT_OFF   ((size_t)226820352)   // 64
#define HOFF_OFF  ((size_t)226820416)   // 64
#define PART_OFF  ((size_t)226820480)   // 98,304
#define BCNT_OFF  ((size_t)226918784)   // 16,384
#define LOCS_OFF  ((size_t)226935168)   // 32,768
#define TOKG_OFF  ((size_t)226967936)   // 32,768
#define WS_NEED   ((size_t)227000704)

extern "C" void kernel_launch(void* const* d_in, const int* in_sizes, int n_in,
                              void* d_out, int out_size, void* d_ws, size_t ws_size,
                              hipStream_t stream) {
  const float* x  = (const float*)d_in[0];
  const float* gw = (const float*)d_in[1];
  const float* gb = (const float*)d_in[2];
  const float* w1 = (const float*)d_in[3];
  const float* b1 = (const float*)d_in[4];
  const float* w2 = (const float*)d_in[5];
  const float* b2 = (const float*)d_in[6];
  float* out = (float*)d_out;
  char* ws = (char*)d_ws;

  if (ws_size < WS_NEED) {
    ws_fail_kernel<<<1, 64, 0, stream>>>(out);
    return;
  }

  unsigned short* xb  = (unsigned short*)(ws + XB_OFF);
  unsigned short* w1t = (unsigned short*)(ws + W1T_OFF);
  unsigned short* yp  = (unsigned short*)(ws + YP_OFF);
  unsigned short* w2t = (unsigned short*)(ws + W2T_OFF);
  unsigned short* h   = (unsigned short*)(ws + H_OFF);
  int*   tmap  = (int*)(ws + TMAP_OFF);
  int*   etok  = (int*)(ws + ET_OFF);
  float* egate = (float*)(ws + EG_OFF);
  int*   ids   = (int*)(ws + IDS_OFF);
  int*   slots = (int*)(ws + SLOT_OFF);
  int*   counts= (int*)(ws + CNT_OFF);
  int*   hoff  = (int*)(ws + HOFF_OFF);
  float* parts = (float*)(ws + PART_OFF);
  int*   bcnt  = (int*)(ws + BCNT_OFF);
  int*   locs  = (int*)(ws + LOCS_OFF);
  float* tokg  = (float*)(ws + TOKG_OFF);

  gate_tr1_kernel<<<GATE_BLKS + TR1_ITEMS, 512, 33280, stream>>>(
      x, gw, gb, ids, locs, tokg, bcnt, parts, xb, w1, w1t);
  meta_kernel<<<1, 1024, 0, stream>>>(bcnt, ids, locs, tokg, parts,
                                      counts, hoff, tmap, etok, egate, slots,
                                      out + (size_t)T_TOK * H_DIM);
  gemm1_kernel<<<G1_ITEMS + TR2_ITEMS, 512, 66560, stream>>>(
      xb, w1t, b1, counts, hoff, tmap, etok, h, w2, w2t);
  gemm2_kernel<<<dim3(4, NT, 3), 512, 65536, stream>>>(h, w2t, b2, hoff, tmap, egate, yp);
  combine_kernel<<<4096, 256, 0, stream>>>(yp, ids, slots, hoff, out);
}

// Round 18
// 286.376 us; speedup vs baseline: 4.8676x; 1.2142x over previous
//
#include <hip/hip_runtime.h>
#include <stdint.h>

#define T_TOK 4096
#define H_DIM 1024
#define E_EXP 8
#define DFF_D 4096
#define HROWS 10240
#define NT 40
#define G1_ITEMS 640          // 16 ct * NT
#define TR2_ITEMS 2048        // w2: 8 e * 4 nt * 64 kt
#define GATE_BLKS 512
#define TR1_ITEMS 2048        // w1: 8 e * 16 nt * 16 kt

typedef __attribute__((ext_vector_type(4))) float f32x4;
typedef __attribute__((ext_vector_type(8))) __bf16 bf16x8;

static __device__ __forceinline__ unsigned short f2bf(float f) {
  union { float f; unsigned u; } v; v.f = f;
  unsigned r = v.u + 0x7FFFu + ((v.u >> 16) & 1u);
  return (unsigned short)(r >> 16);
}
static __device__ __forceinline__ float bf2f(unsigned short u) {
  union { unsigned u; float f; } v; v.u = ((unsigned)u) << 16; return v.f;
}
static __device__ __forceinline__ void load_lds16(const void* g, void* l) {
  __builtin_amdgcn_global_load_lds(
      (const __attribute__((address_space(1))) unsigned int*)g,
      (__attribute__((address_space(3))) unsigned int*)l, 16, 0, 0);
}

#define MEMF() asm volatile("" ::: "memory")
#define BAR()  { MEMF(); __builtin_amdgcn_s_barrier(); MEMF(); }
#define VM4()  asm volatile("s_waitcnt vmcnt(4)" ::: "memory")
#define VM2()  asm volatile("s_waitcnt vmcnt(2)" ::: "memory")
#define VM0()  asm volatile("s_waitcnt vmcnt(0)" ::: "memory")
#define SP1()  __builtin_amdgcn_s_setprio(1)
#define SP0()  __builtin_amdgcn_s_setprio(0)

// ---- R11-verified: transpose 64x256 src tile -> one 32KB consumption-order B tile ----
static __device__ __forceinline__ void tr_tile_to_tiled(
    unsigned short* __restrict__ tile16,         // LDS [64][260] ushort
    const float* __restrict__ src, int src_ld,
    int r0, int c0,                              // src row(k)/col(n) base
    unsigned short* __restrict__ tile_out,       // 32KB block
    int tid) {
  const int w = tid >> 6, lane = tid & 63;
#pragma unroll
  for (int i = 0; i < 8; ++i) {
    const int row = w * 8 + i;
    float4 v = *(const float4*)&src[(size_t)(r0 + row) * src_ld + c0 + 4 * lane];
    ushort4 o;
    o.x = f2bf(v.x); o.y = f2bf(v.y); o.z = f2bf(v.z); o.w = f2bf(v.w);
    *(ushort4*)&tile16[row * 260 + 4 * lane] = o;
  }
  __syncthreads();
  const int r0t = ((tid >> 7) << 4) + ((tid >> 2) & 15);
  const int kbt = (((tid >> 6) & 1) << 5) + (((tid & 3) << 3) ^ (((tid >> 5) & 1) << 4));
#pragma unroll
  for (int half = 0; half < 2; ++half)
#pragma unroll
    for (int j = 0; j < 2; ++j) {
      const int c = half * 128 + 64 * j + r0t;
      unsigned ow[4];
#pragma unroll
      for (int p = 0; p < 4; ++p)
        ow[p] = (unsigned)tile16[(kbt + 2 * p) * 260 + c]
              | ((unsigned)tile16[(kbt + 2 * p + 1) * 260 + c] << 16);
      *(uint4*)((char*)tile_out + half * 16384 + j * 8192 + tid * 16) = *(uint4*)ow;
    }
}

// ---------------- fused: gate (atomic-free) + w1 transpose ----------------
__global__ __launch_bounds__(512) void gate_tr1_kernel(
    const float* __restrict__ x, const float* __restrict__ gw,
    const float* __restrict__ gb,
    int* __restrict__ ids, int* __restrict__ locs, float* __restrict__ tokg,
    int* __restrict__ bcnt, float* __restrict__ partials,
    unsigned short* __restrict__ xb,
    const float* __restrict__ w1, unsigned short* __restrict__ w1t) {
  extern __shared__ char smem[];
  const int tid = threadIdx.x;
  const int blk = blockIdx.x;

  if (blk >= GATE_BLKS) {
    const int j = blk - GATE_BLKS;               // [0, 2048)
    const int e2 = j >> 8;
    const int jj = j & 255;
    const int nt = jj >> 4, kt = jj & 15;
    tr_tile_to_tiled((unsigned short*)smem,
                     w1 + (size_t)e2 * H_DIM * DFF_D, DFF_D,
                     kt * 64, nt * 256,
                     w1t + ((size_t)((e2 * 16 + nt) * 16 + kt)) * 16384,
                     tid);
    return;
  }

  // ---- gate (atomic-free, deterministic intra-block ranking) ----
  float (*probs_lds)[8] = (float(*)[8])smem;              // [8][8]
  int   (*topi_lds)[2]  = (int(*)[2])(smem + 256);        // [8][2]
  int*  locs_lds        = (int*)(smem + 320);             // [16]
  int*  cnt_lds         = (int*)(smem + 384);             // [8]
  const int lane = tid & 63, tl = tid >> 6;
  const int token = blk * 8 + tl;
  float a[8];
#pragma unroll
  for (int e = 0; e < 8; ++e) a[e] = 0.f;
#pragma unroll
  for (int i = 0; i < 4; ++i) {
    const int k4 = i * 256 + lane * 4;
    float4 xv4 = *(const float4*)&x[(size_t)token * H_DIM + k4];
    ushort4 xo;
    xo.x = f2bf(xv4.x); xo.y = f2bf(xv4.y); xo.z = f2bf(xv4.z); xo.w = f2bf(xv4.w);
    *(ushort4*)&xb[(size_t)token * H_DIM + k4] = xo;
#pragma unroll
    for (int j = 0; j < 4; ++j) {
      const float xv = ((const float*)&xv4)[j];
      const float4* g = (const float4*)&gw[(size_t)(k4 + j) * 8];
      float4 g0 = g[0], g1 = g[1];
      a[0] += xv * g0.x; a[1] += xv * g0.y; a[2] += xv * g0.z; a[3] += xv * g0.w;
      a[4] += xv * g1.x; a[5] += xv * g1.y; a[6] += xv * g1.z; a[7] += xv * g1.w;
    }
  }
  for (int m = 32; m >= 1; m >>= 1) {
#pragma unroll
    for (int e = 0; e < 8; ++e) a[e] += __shfl_xor(a[e], m);
  }
  if (lane == 0) {
    float lg[8], p[8];
    float mx = -1e30f;
#pragma unroll
    for (int e = 0; e < 8; ++e) { lg[e] = a[e] + gb[e]; mx = lg[e] > mx ? lg[e] : mx; }
    float s = 0.f;
#pragma unroll
    for (int e = 0; e < 8; ++e) { p[e] = expf(lg[e] - mx); s += p[e]; }
    float inv = 1.f / s;
#pragma unroll
    for (int e = 0; e < 8; ++e) p[e] *= inv;
    int i0 = 0;
#pragma unroll
    for (int e = 1; e < 8; ++e) if (p[e] > p[i0]) i0 = e;
    int i1 = (i0 == 0) ? 1 : 0;
#pragma unroll
    for (int e = 0; e < 8; ++e) if (e != i0 && p[e] > p[i1]) i1 = e;
#pragma unroll
    for (int e = 0; e < 8; ++e) probs_lds[tl][e] = p[e];
    topi_lds[tl][0] = i0; topi_lds[tl][1] = i1;
  }
  __syncthreads();
  if (tid == 0) {
    int run[8];
#pragma unroll
    for (int e = 0; e < 8; ++e) run[e] = 0;
    for (int q = 0; q < 16; ++q) {
      const int e = topi_lds[q >> 1][q & 1];
      locs_lds[q] = run[e]++;
    }
#pragma unroll
    for (int e = 0; e < 8; ++e) cnt_lds[e] = run[e];
  }
  __syncthreads();
  if (tid < 16) {
    const int tt = tid >> 1, c = tid & 1;
    const int t2 = blk * 8 + tt;
    const int e = topi_lds[tt][c];
    ids[t2 * 2 + c]  = e;
    locs[t2 * 2 + c] = locs_lds[tid];
    tokg[t2 * 2 + c] = probs_lds[tt][e];
  }
  if (tid >= 16 && tid < 24) bcnt[blk * 8 + (tid - 16)] = cnt_lds[tid - 16];
  if (tid < 24) {
    int e = tid & 7, which = tid >> 3;
    float s = 0.f;
#pragma unroll
    for (int tt = 0; tt < 8; ++tt) {
      float pv = probs_lds[tt][e];
      bool m = (topi_lds[tt][0] == e) || (topi_lds[tt][1] == e);
      if (which == 0) s += pv;
      else if (which == 1) s += m ? 1.f : 0.f;
      else s += m ? pv : 0.f;
    }
    partials[blk * 24 + tid] = s;
  }
}

// ---------------- meta: scan + scatter + offsets/tilemap + aux ----------------
__global__ __launch_bounds__(1024) void meta_kernel(
    const int* __restrict__ bcnt, const int* __restrict__ ids,
    const int* __restrict__ locs, const float* __restrict__ tokg,
    const float* __restrict__ partials,
    int* __restrict__ counts, int* __restrict__ hoff, int* __restrict__ tmap,
    int* __restrict__ entry_token, float* __restrict__ entry_gate,
    int* __restrict__ slots, float* __restrict__ out_aux) {
  __shared__ int sc[8][513];
  __shared__ float red[24][33];
  const int tid = threadIdx.x;
#pragma unroll
  for (int j = 0; j < 4; ++j) {
    const int idx = tid + j * 1024;
    const int e = idx >> 9, b = idx & 511;
    sc[e][b] = bcnt[b * 8 + e];
  }
  __syncthreads();
  for (int off = 1; off < 512; off <<= 1) {
    int v[4];
#pragma unroll
    for (int j = 0; j < 4; ++j) {
      const int idx = tid + j * 1024;
      const int e = idx >> 9, b = idx & 511;
      v[j] = sc[e][b] + (b >= off ? sc[e][b - off] : 0);
    }
    __syncthreads();
#pragma unroll
    for (int j = 0; j < 4; ++j) {
      const int idx = tid + j * 1024;
      sc[idx >> 9][idx & 511] = v[j];
    }
    __syncthreads();
  }
  if (tid == 0) {
    int o = 0, nt = 0;
    for (int e = 0; e < E_EXP; ++e) {
      const int ce = sc[e][511];
      counts[e] = ce;
      hoff[e] = o;
      int rtc = (ce + 255) >> 8;
      o += rtc << 8;
      for (int rt = 0; rt < rtc; ++rt) tmap[nt++] = (e << 16) | rt;
    }
    hoff[E_EXP] = o;
    for (; nt < NT; ++nt) tmap[nt] = -1;
  }
  __syncthreads();
#pragma unroll
  for (int j = 0; j < 8; ++j) {
    const int idx = tid + j * 1024;
    const int t = idx >> 1, c = idx & 1, b = t >> 3;
    const int e = ids[t * 2 + c];
    const int slot = sc[e][b] - bcnt[b * 8 + e] + locs[t * 2 + c];
    entry_token[e * T_TOK + slot] = t;
    entry_gate[e * T_TOK + slot] = tokg[t * 2 + c];
    slots[t * 2 + c] = slot;
  }
  const int c = tid & 31, g = tid >> 5;
  if (c < 24) {
    float s = 0.f;
    for (int j = 0; j < 16; ++j) s += partials[(size_t)(g + j * 32) * 24 + c];
    red[c][g] = s;
  }
  __syncthreads();
  if (tid < 24) {
    float t2 = 0.f;
#pragma unroll
    for (int g2 = 0; g2 < 32; ++g2) t2 += red[tid][g2];
    red[tid][32] = t2;
  }
  __syncthreads();
  if (tid == 0) {
    float mean = 0.f;
    for (int e = 0; e < 8; ++e) mean += red[e][32];
    mean *= 0.125f;
    float var = 0.f;
    for (int e = 0; e < 8; ++e) { float d = red[e][32] - mean; var += d * d; }
    var *= (1.f / 7.f);
    float il = var * (1.f / 64.f);
    float lb = 0.f;
    for (int e = 0; e < 8; ++e)
      lb += (red[8 + e][32] / (float)T_TOK) * (red[16 + e][32] / (float)T_TOK);
    lb *= 8.f;
    out_aux[0] = il + lb;
  }
}

// ======== 256x256x64 deep-flight 4-phase grouped-GEMM machinery (R11) ========
#define STG_A0(m_) { char* lb_ = sA + ((m_)&1)*32768 + wv*1024; \
  load_lds16(pa0s0 + (size_t)(m_)*128, lb_); load_lds16(pa0s1 + (size_t)(m_)*128, lb_ + 8192); }
#define STG_A1(m_) { char* lb_ = sA + ((m_)&1)*32768 + 16384 + wv*1024; \
  load_lds16(pa1s0 + (size_t)(m_)*128, lb_); load_lds16(pa1s1 + (size_t)(m_)*128, lb_ + 8192); }
#define STG_B0(m_) { char* lb_ = sB + ((m_)&1)*32768 + wv*1024; \
  load_lds16(pb0s0 + (size_t)(m_)*32768, lb_); load_lds16(pb0s1 + (size_t)(m_)*32768, lb_ + 8192); }
#define STG_B1(m_) { char* lb_ = sB + ((m_)&1)*32768 + 16384 + wv*1024; \
  load_lds16(pb1s0 + (size_t)(m_)*32768, lb_); load_lds16(pb1s1 + (size_t)(m_)*32768, lb_ + 8192); }

#define LDA8(DST, AD) \
  _Pragma("unroll") for (int mi = 0; mi < 4; ++mi) \
  _Pragma("unroll") for (int kk = 0; kk < 2; ++kk) \
    DST[mi][kk] = *(const bf16x8*)((AD) + (amfrag + mi) * 2048 + kk * 1024 + lane_off);
#define LDB4(DST, BD) \
  _Pragma("unroll") for (int ni = 0; ni < 2; ++ni) \
  _Pragma("unroll") for (int kk = 0; kk < 2; ++kk) \
    DST[ni][kk] = *(const bf16x8*)((BD) + (bnfrag + ni) * 2048 + kk * 1024 + lane_off);
#define MF16(ACC, AF, BF) \
  _Pragma("unroll") for (int mi = 0; mi < 4; ++mi) \
  _Pragma("unroll") for (int ni = 0; ni < 2; ++ni) \
  _Pragma("unroll") for (int kk = 0; kk < 2; ++kk) \
    ACC[mi][ni] = __builtin_amdgcn_mfma_f32_16x16x32_bf16(AF[mi][kk], BF[ni][kk], ACC[mi][ni], 0, 0, 0);

#define ACC_INIT() \
  f32x4 q00[4][2], q01[4][2], q10[4][2], q11[4][2]; \
  _Pragma("unroll") for (int mi = 0; mi < 4; ++mi) \
  _Pragma("unroll") for (int ni = 0; ni < 2; ++ni) { \
    q00[mi][ni] = (f32x4){0.f,0.f,0.f,0.f}; q01[mi][ni] = (f32x4){0.f,0.f,0.f,0.f}; \
    q10[mi][ni] = (f32x4){0.f,0.f,0.f,0.f}; q11[mi][ni] = (f32x4){0.f,0.f,0.f,0.f}; }

#define PROLOGUE() \
  STG_A0(0); STG_B0(0); STG_B1(0); STG_A1(0); \
  VM0(); \
  BAR();

#define KLOOP_DEEP(KT) \
  for (int k = 0; k < (KT); ++k) { \
    const char* Ab = sA + (k & 1) * 32768; \
    const char* Bb = sB + (k & 1) * 32768; \
    bf16x8 alo[4][2], ahi[4][2], blo[2][2], bhi[2][2]; \
    LDA8(alo, Ab); LDB4(blo, Bb); \
    if (k + 1 < (KT)) STG_A0(k + 1); \
    BAR(); \
    SP1(); MF16(q00, alo, blo); SP0(); \
    if (k + 1 < (KT)) { VM4(); } else { VM2(); } \
    BAR(); \
    LDB4(bhi, Bb + 16384); \
    if (k + 1 < (KT)) STG_B0(k + 1); \
    BAR(); \
    SP1(); MF16(q01, alo, bhi); SP0(); \
    if (k + 1 < (KT)) { VM4(); } else { VM0(); } \
    BAR(); \
    LDA8(ahi, Ab + 16384); \
    if (k + 1 < (KT)) STG_B1(k + 1); \
    BAR(); \
    SP1(); MF16(q10, ahi, blo); SP0(); \
    BAR(); \
    if (k + 1 < (KT)) STG_A1(k + 1); \
    BAR(); \
    SP1(); MF16(q11, ahi, bhi); SP0(); \
    VM4(); \
    BAR(); \
  }

// ---------------- GEMM1 (+ fused w2 transpose items in tail blocks) ----------------
__global__ __launch_bounds__(512, 2) void gemm1_kernel(
    const unsigned short* __restrict__ xb,    // [T][1024]
    const unsigned short* __restrict__ w1t,   // TILED [E][16 nt][16 kt][32KB]
    const float* __restrict__ b1,
    const int* __restrict__ counts, const int* __restrict__ hoff,
    const int* __restrict__ tmap, const int* __restrict__ entry_token,
    unsigned short* __restrict__ h,           // [HROWS][4096]
    const float* __restrict__ w2,             // [E][4096][1024] f32
    unsigned short* __restrict__ w2t)         // TILED [E][4 nt][64 kt][32KB]
{
  extern __shared__ char smem[];
  char* sA = smem;
  char* sB = smem + 65536;
  const int tid = threadIdx.x;
  const int item = blockIdx.x;

  if (item >= G1_ITEMS) {
    const int j = item - G1_ITEMS;            // [0, 2048)
    const int e2 = j >> 8;
    const int jj = j & 255;
    const int nt = jj >> 6, kt = jj & 63;
    tr_tile_to_tiled((unsigned short*)smem,
                     w2 + (size_t)e2 * DFF_D * H_DIM, H_DIM,
                     kt * 64, nt * 256,
                     w2t + ((size_t)((e2 * 4 + nt) * 64 + kt)) * 16384,
                     tid);
    return;
  }

  int* tok = (int*)(smem + 131072);
  int lin = item;
  lin = (lin & 7) * (G1_ITEMS / 8) + (lin >> 3);  // bijective XCD swizzle (640%8==0)
  const int ti = lin % NT, ct = lin / NT;
  const int mEnc = tmap[ti];
  if (mEnc < 0) return;
  const int e = mEnc >> 16, rt = mEnc & 0xffff;
  const int cnt = counts[e];
  const int lane = tid & 63, wv = tid >> 6;
  if (tid < 256) {
    int s = rt * 256 + tid;
    if (s >= cnt) s = cnt - 1;
    tok[tid] = entry_token[e * T_TOK + s];
  }
  __syncthreads();
  const int r0 = ((tid >> 7) << 4) + ((tid >> 2) & 15);                       // [0,64)
  const int kb = (((tid >> 6) & 1) << 5) + (((tid & 3) << 3) ^ (((tid >> 5) & 1) << 4));
  const char* xbb = (const char*)xb;
  const char* pa0s0 = xbb + (size_t)tok[r0]       * 2048 + kb * 2;
  const char* pa0s1 = xbb + (size_t)tok[64 + r0]  * 2048 + kb * 2;
  const char* pa1s0 = xbb + (size_t)tok[128 + r0] * 2048 + kb * 2;
  const char* pa1s1 = xbb + (size_t)tok[192 + r0] * 2048 + kb * 2;
  const char* w1e = (const char*)w1t + ((size_t)(e * 16 + ct) * 16) * 32768;
  const char* pb0s0 = w1e + tid * 16;
  const char* pb0s1 = w1e + 8192 + tid * 16;
  const char* pb1s0 = w1e + 16384 + tid * 16;
  const char* pb1s1 = w1e + 24576 + tid * 16;
  const int amfrag = (wv >> 2) * 4;
  const int bnfrag = (wv & 3) * 2;
  const int mb0 = (wv >> 2) * 64, nb0 = (wv & 3) * 32;
  const int lane_off = (lane & 15) * 64 + ((((lane >> 4) << 3) ^ (((lane >> 3) & 1) << 4)) << 1);
  ACC_INIT()
  PROLOGUE()
  KLOOP_DEEP(16)
  const int rb = hoff[e] + rt * 256;
  const float* b1e = b1 + (size_t)e * DFF_D;
#define EPI1(ACC, A_, B_) \
  _Pragma("unroll") for (int mi = 0; mi < 4; ++mi) \
  _Pragma("unroll") for (int ni = 0; ni < 2; ++ni) { \
    const int n = ct * 256 + (B_) * 128 + nb0 + ni * 16 + (lane & 15); \
    const float bias = b1e[n]; \
    _Pragma("unroll") for (int q = 0; q < 4; ++q) { \
      const int m = (A_) * 128 + mb0 + mi * 16 + (lane >> 4) * 4 + q; \
      float v = ACC[mi][ni][q] + bias; v = v > 0.f ? v : 0.f; \
      h[(size_t)(rb + m) * DFF_D + n] = f2bf(v); \
    } }
  EPI1(q00, 0, 0) EPI1(q01, 0, 1) EPI1(q10, 1, 0) EPI1(q11, 1, 1)
#undef EPI1
}

// ---------------- GEMM2: yp[part] = gate * (h @ w2^T (+ b2)) , split-K=3 ----------------
__global__ __launch_bounds__(512, 2) void gemm2_kernel(
    const unsigned short* __restrict__ h,     // [HROWS][4096]
    const unsigned short* __restrict__ w2t,   // TILED [E][4 nt][64 kt][32KB]
    const float* __restrict__ b2,
    const int* __restrict__ hoff, const int* __restrict__ tmap,
    const float* __restrict__ entry_gate,
    unsigned short* __restrict__ yp)          // [3][HROWS][1024]
{
  extern __shared__ char smem[];
  char* sA = smem;
  char* sB = smem + 65536;
  int lin = (blockIdx.z * NT + blockIdx.y) * 4 + blockIdx.x;  // nwg = 480
  lin = (lin & 7) * (3 * NT * 4 / 8) + (lin >> 3);            // bijective
  const int ct = lin & 3;
  const int g = lin >> 2;
  const int ti = g % NT, part = g / NT;
  const int mEnc = tmap[ti];
  if (mEnc < 0) return;
  const int e = mEnc >> 16, rt = mEnc & 0xffff;
  int S, KT;
  if (part == 0)      { S = 0;  KT = 22; }
  else if (part == 1) { S = 22; KT = 21; }
  else                { S = 43; KT = 21; }
  const int tid = threadIdx.x, lane = tid & 63, wv = tid >> 6;
  const int rb = hoff[e] + rt * 256;
  const int r0 = ((tid >> 7) << 4) + ((tid >> 2) & 15);
  const int kb = (((tid >> 6) & 1) << 5) + (((tid & 3) << 3) ^ (((tid >> 5) & 1) << 4));
  const char* hb = (const char*)h + (size_t)S * 128;
  const char* pa0s0 = hb + (size_t)(rb + r0)       * 8192 + kb * 2;
  const char* pa0s1 = hb + (size_t)(rb + 64 + r0)  * 8192 + kb * 2;
  const char* pa1s0 = hb + (size_t)(rb + 128 + r0) * 8192 + kb * 2;
  const char* pa1s1 = hb + (size_t)(rb + 192 + r0) * 8192 + kb * 2;
  const char* w2e = (const char*)w2t + ((size_t)((e * 4 + ct) * 64 + S)) * 32768;
  const char* pb0s0 = w2e + tid * 16;
  const char* pb0s1 = w2e + 8192 + tid * 16;
  const char* pb1s0 = w2e + 16384 + tid * 16;
  const char* pb1s1 = w2e + 24576 + tid * 16;
  const int amfrag = (wv >> 2) * 4;
  const int bnfrag = (wv & 3) * 2;
  const int mb0 = (wv >> 2) * 64, nb0 = (wv & 3) * 32;
  const int lane_off = (lane & 15) * 64 + ((((lane >> 4) << 3) ^ (((lane >> 3) & 1) << 4)) << 1);
  ACC_INIT()
  PROLOGUE()
  KLOOP_DEEP(KT)
  unsigned short* yout = yp + (size_t)part * HROWS * H_DIM;
  const float* b2e = b2 + (size_t)e * H_DIM;
  const float* ge = entry_gate + (size_t)e * T_TOK + rt * 256;
#define EPI2(ACC, A_, B_) \
  _Pragma("unroll") for (int mi = 0; mi < 4; ++mi) \
  _Pragma("unroll") for (int ni = 0; ni < 2; ++ni) { \
    const int n = ct * 256 + (B_) * 128 + nb0 + ni * 16 + (lane & 15); \
    const float bias = (part == 0) ? b2e[n] : 0.f; \
    _Pragma("unroll") for (int q = 0; q < 4; ++q) { \
      const int m = (A_) * 128 + mb0 + mi * 16 + (lane >> 4) * 4 + q; \
      const float gate = ge[m];  /* pad rows: garbage, never combined */ \
      float v = (ACC[mi][ni][q] + bias) * gate; \
      yout[(size_t)(rb + m) * H_DIM + n] = f2bf(v); \
    } }
  EPI2(q00, 0, 0) EPI2(q01, 0, 1) EPI2(q10, 1, 0) EPI2(q11, 1, 1)
#undef EPI2
}

// ---------------- combine: out[t] = sum_{p,k} yp[p][row(t,k)] ----------------
__global__ void combine_kernel(const unsigned short* __restrict__ yp,
                               const int* __restrict__ ids, const int* __restrict__ slots,
                               const int* __restrict__ hoff, float* __restrict__ out) {
  const int t = blockIdx.x, tid = threadIdx.x;
  const int r0 = hoff[ids[t * 2]] + slots[t * 2];
  const int r1 = hoff[ids[t * 2 + 1]] + slots[t * 2 + 1];
  const int c = tid * 4;
  float4 o = {0.f, 0.f, 0.f, 0.f};
#pragma unroll
  for (int p = 0; p < 3; ++p) {
    const unsigned short* pl = yp + (size_t)p * HROWS * H_DIM;
    ushort4 a = *(const ushort4*)&pl[(size_t)r0 * H_DIM + c];
    ushort4 b = *(const ushort4*)&pl[(size_t)r1 * H_DIM + c];
    o.x += bf2f(a.x) + bf2f(b.x);
    o.y += bf2f(a.y) + bf2f(b.y);
    o.z += bf2f(a.z) + bf2f(b.z);
    o.w += bf2f(a.w) + bf2f(b.w);
  }
  *(float4*)&out[(size_t)t * H_DIM + c] = o;
}

__global__ void ws_fail_kernel(float* out) {
  if (threadIdx.x == 0 && blockIdx.x == 0) out[0] = -12345.0f;
}

// ---------------- workspace layout (bytes) ----------------
#define XB_OFF    ((size_t)0)           // 8,388,608   (dead after gemm1)
#define W1T_OFF   ((size_t)8388608)     // 67,108,864  (dead after gemm1)
#define YP_OFF    ((size_t)0)           // 3*10240*1024*2 = 62,914,560 (aliases xb+w1t)
#define W2T_OFF   ((size_t)75497472)    // 67,108,864
#define H_OFF     ((size_t)142606336)   // 83,886,080
#define TMAP_OFF  ((size_t)226492416)   // 256
#define ET_OFF    ((size_t)226492672)   // 131,072
#define EG_OFF    ((size_t)226623744)   // 131,072
#define IDS_OFF   ((size_t)226754816)   // 32,768
#define SLOT_OFF  ((size_t)226787584)   // 32,768
#define CNT_OFF   ((size_t)226820352)   // 64
#define HOFF_OFF  ((size_t)226820416)   // 64
#define PART_OFF  ((size_t)226820480)   // 98,304
#define BCNT_OFF  ((size_t)226918784)   // 16,384
#define LOCS_OFF  ((size_t)226935168)   // 32,768
#define TOKG_OFF  ((size_t)226967936)   // 32,768
#define WS_NEED   ((size_t)227000704)

extern "C" void kernel_launch(void* const* d_in, const int* in_sizes, int n_in,
                              void* d_out, int out_size, void* d_ws, size_t ws_size,
                              hipStream_t stream) {
  const float* x  = (const float*)d_in[0];
  const float* gw = (const float*)d_in[1];
  const float* gb = (const float*)d_in[2];
  const float* w1 = (const float*)d_in[3];
  const float* b1 = (const float*)d_in[4];
  const float* w2 = (const float*)d_in[5];
  const float* b2 = (const float*)d_in[6];
  float* out = (float*)d_out;
  char* ws = (char*)d_ws;

  if (ws_size < WS_NEED) {
    ws_fail_kernel<<<1, 64, 0, stream>>>(out);
    return;
  }

  unsigned short* xb  = (unsigned short*)(ws + XB_OFF);
  unsigned short* w1t = (unsigned short*)(ws + W1T_OFF);
  unsigned short* yp  = (unsigned short*)(ws + YP_OFF);
  unsigned short* w2t = (unsigned short*)(ws + W2T_OFF);
  unsigned short* h   = (unsigned short*)(ws + H_OFF);
  int*   tmap  = (int*)(ws + TMAP_OFF);
  int*   etok  = (int*)(ws + ET_OFF);
  float* egate = (float*)(ws + EG_OFF);
  int*   ids   = (int*)(ws + IDS_OFF);
  int*   slots = (int*)(ws + SLOT_OFF);
  int*   counts= (int*)(ws + CNT_OFF);
  int*   hoff  = (int*)(ws + HOFF_OFF);
  float* parts = (float*)(ws + PART_OFF);
  int*   bcnt  = (int*)(ws + BCNT_OFF);
  int*   locs  = (int*)(ws + LOCS_OFF);
  float* tokg  = (float*)(ws + TOKG_OFF);

  gate_tr1_kernel<<<GATE_BLKS + TR1_ITEMS, 512, 33280, stream>>>(
      x, gw, gb, ids, locs, tokg, bcnt, parts, xb, w1, w1t);
  meta_kernel<<<1, 1024, 0, stream>>>(bcnt, ids, locs, tokg, parts,
                                      counts, hoff, tmap, etok, egate, slots,
                                      out + (size_t)T_TOK * H_DIM);
  gemm1_kernel<<<G1_ITEMS + TR2_ITEMS, 512, 132096, stream>>>(
      xb, w1t, b1, counts, hoff, tmap, etok, h, w2, w2t);
  gemm2_kernel<<<dim3(4, NT, 3), 512, 131072, stream>>>(h, w2t, b2, hoff, tmap, egate, yp);
  combine_kernel<<<4096, 256, 0, stream>>>(yp, ids, slots, hoff, out);
}